// Round 2
// baseline (273.273 us; speedup 1.0000x reference)
//
#include <hip/hip_runtime.h>

// Problem constants (fixed by the reference):
//   B=128, L=9, K=3, C_IN=C_OUT=256, P=1680 (perms of [0,0,0,1,1,1,2,2,2], lex order)
#define B_DIM 128
#define L_DIM 9
#define K_DIM 3
#define C 256
#define P_TOT 1680
#define R_DIM 27          // L*K rows of Z per batch
#define TILE_P 80
#define TILES 21          // 1680 / 80

// Workspace layout (bytes):
//   [0, 60480)        jidx  : int[P*L], row index r = l*3 + idx[p,l] in [0,27)
//   [61440, 68160)    dpos  : int[P], first l where perm p differs from perm p-1 (0 for p=0)
//   [131072, +3.54MB) Z     : float[B*27*256], Z[b][r][o]
#define WS_DPOS_OFF 61440
#define WS_Z_OFF 131072

typedef float vfloat4 __attribute__((ext_vector_type(4)));  // native vec for nontemporal builtins

__device__ inline float4 add4(float4 a, float4 b) {
    return make_float4(a.x + b.x, a.y + b.y, a.z + b.z, a.w + b.w);
}

// ---------------------------------------------------------------- prep ----
// Derive per-permutation row indices and prefix-diff depth from the one-hot
// mask M (K,P,L).  idx[p,l] = argmax_a M[a,p,l] = M[1,p,l] + 2*M[2,p,l].
__global__ void prep_kernel(const float* __restrict__ M,
                            int* __restrict__ jidx,
                            int* __restrict__ dpos) {
    int p = blockIdx.x * blockDim.x + threadIdx.x;
    if (p >= P_TOT) return;
    int cur[L_DIM];
#pragma unroll
    for (int l = 0; l < L_DIM; ++l) {
        float m1 = M[(1 * P_TOT + p) * L_DIM + l];
        float m2 = M[(2 * P_TOT + p) * L_DIM + l];
        int a = (int)(m1 + 2.0f * m2 + 0.5f);
        cur[l] = l * K_DIM + a;
        jidx[p * L_DIM + l] = cur[l];
    }
    int d = 0;
    if (p > 0) {
        while (d < L_DIM) {
            float m1 = M[(1 * P_TOT + (p - 1)) * L_DIM + d];
            float m2 = M[(2 * P_TOT + (p - 1)) * L_DIM + d];
            int pr = d * K_DIM + (int)(m1 + 2.0f * m2 + 0.5f);
            if (pr != cur[d]) break;
            ++d;
        }
    }
    dpos[p] = d;
}

// ------------------------------------------------------------- z_kernel ----
// Z[b][l*3+a][o] = sum_c x[b,l,c] * W[a,o,c].
// Grid 768 = B * 3 (a) * 2 (o-half); 128 threads, one o per thread.
__global__ __launch_bounds__(128) void z_kernel(const float* __restrict__ x,
                                                const float* __restrict__ W,
                                                float* __restrict__ Z) {
    int bid = blockIdx.x;
    int b = bid / 6;
    int rem = bid % 6;
    int a = rem >> 1;
    int half = rem & 1;
    int o = half * 128 + threadIdx.x;

    const float4* __restrict__ W4 = (const float4*)(W + (size_t)(a * C + o) * C);
    const float4* __restrict__ X4 = (const float4*)(x + (size_t)b * L_DIM * C);

    float acc[L_DIM];
#pragma unroll
    for (int l = 0; l < L_DIM; ++l) acc[l] = 0.0f;

#pragma unroll 4
    for (int c4 = 0; c4 < C / 4; ++c4) {
        float4 wv = W4[c4];
#pragma unroll
        for (int l = 0; l < L_DIM; ++l) {
            float4 xv = X4[l * (C / 4) + c4];  // uniform across block
            acc[l] += wv.x * xv.x + wv.y * xv.y + wv.z * xv.z + wv.w * xv.w;
        }
    }
    float* zb = Z + (size_t)b * R_DIM * C;
#pragma unroll
    for (int l = 0; l < L_DIM; ++l) {
        zb[(l * K_DIM + a) * C + o] = acc[l];
    }
}

// ------------------------------------------------------------- y_kernel ----
// y[b,p,:] = sum_l Z[b, jidx[p,l], :].  One block per (b, tile of 80 p's).
// Z[b] (27KB) staged in LDS.  Each wave takes 20 *consecutive* p's; running
// prefix partials p0..p8 (float4/lane = full 256-ch row per wave) live in
// registers, and only suffix levels >= dpos[p] are recomputed (lex-order
// prefix sharing: ~3.1 LDS row reads per p instead of 9).
__global__ __launch_bounds__(256) void y_kernel(const float* __restrict__ Z,
                                                const int* __restrict__ jidx,
                                                const int* __restrict__ dpos,
                                                float* __restrict__ out) {
    __shared__ float Zs[R_DIM * C];          // 27 KB
    __shared__ int jr[TILE_P * L_DIM];       // 2880 B
    __shared__ int dp[TILE_P];               // 320 B

    int bid = blockIdx.x;
    int b = bid / TILES;
    int tile = bid % TILES;
    int base = tile * TILE_P;

    const float4* Zb4 = (const float4*)(Z + (size_t)b * R_DIM * C);
    float4* Zs4 = (float4*)Zs;
    for (int i = threadIdx.x; i < R_DIM * (C / 4); i += 256) Zs4[i] = Zb4[i];
    for (int i = threadIdx.x; i < TILE_P * L_DIM; i += 256) jr[i] = jidx[base * L_DIM + i];
    if (threadIdx.x < TILE_P) dp[threadIdx.x] = dpos[base + threadIdx.x];
    __syncthreads();

    int wave = threadIdx.x >> 6;
    int lane = threadIdx.x & 63;
    const float4* zsr = (const float4*)Zs;
    vfloat4* out4 = (vfloat4*)out;

    float4 p0, p1, p2, p3, p4, p5, p6, p7, p8;

    int pl = wave * (TILE_P / 4);
    for (int j = 0; j < TILE_P / 4; ++j, ++pl) {
        // wave-uniform resume depth: 0 for the wave's first p (prev p not ours)
        int k = (j == 0) ? 0 : __builtin_amdgcn_readfirstlane(dp[pl]);
        const int* rr = &jr[pl * L_DIM];
        switch (k) {
            case 0: p0 = zsr[__builtin_amdgcn_readfirstlane(rr[0]) * 64 + lane]; [[fallthrough]];
            case 1: p1 = add4(p0, zsr[__builtin_amdgcn_readfirstlane(rr[1]) * 64 + lane]); [[fallthrough]];
            case 2: p2 = add4(p1, zsr[__builtin_amdgcn_readfirstlane(rr[2]) * 64 + lane]); [[fallthrough]];
            case 3: p3 = add4(p2, zsr[__builtin_amdgcn_readfirstlane(rr[3]) * 64 + lane]); [[fallthrough]];
            case 4: p4 = add4(p3, zsr[__builtin_amdgcn_readfirstlane(rr[4]) * 64 + lane]); [[fallthrough]];
            case 5: p5 = add4(p4, zsr[__builtin_amdgcn_readfirstlane(rr[5]) * 64 + lane]); [[fallthrough]];
            case 6: p6 = add4(p5, zsr[__builtin_amdgcn_readfirstlane(rr[6]) * 64 + lane]); [[fallthrough]];
            case 7: p7 = add4(p6, zsr[__builtin_amdgcn_readfirstlane(rr[7]) * 64 + lane]); [[fallthrough]];
            case 8: p8 = add4(p7, zsr[__builtin_amdgcn_readfirstlane(rr[8]) * 64 + lane]); break;
            default: break;
        }
        // coalesced 1KB/wave nontemporal store (output is write-once streaming)
        int orow = b * P_TOT + base + pl;
        vfloat4 sv = {p8.x, p8.y, p8.z, p8.w};
        __builtin_nontemporal_store(sv, &out4[(size_t)orow * 64 + lane]);
    }
}

// ------------------------------------------------------------------ launch --
extern "C" void kernel_launch(void* const* d_in, const int* in_sizes, int n_in,
                              void* d_out, int out_size, void* d_ws, size_t ws_size,
                              hipStream_t stream) {
    const float* x = (const float*)d_in[0];  // (128, 9, 256)
    const float* W = (const float*)d_in[1];  // (3, 256, 256)
    const float* M = (const float*)d_in[2];  // (3, 1680, 9)
    float* out = (float*)d_out;              // (128, 1680, 256)

    int* jidx = (int*)d_ws;
    int* dpos = (int*)((char*)d_ws + WS_DPOS_OFF);
    float* Z = (float*)((char*)d_ws + WS_Z_OFF);

    prep_kernel<<<(P_TOT + 255) / 256, 256, 0, stream>>>(M, jidx, dpos);
    z_kernel<<<B_DIM * K_DIM * 2, 128, 0, stream>>>(x, W, Z);
    y_kernel<<<B_DIM * TILES, 256, 0, stream>>>(Z, jidx, dpos, out);
}